// Round 10
// baseline (271.124 us; speedup 1.0000x reference)
//
#include <hip/hip_runtime.h>
#include <math.h>

#define NSITES 27
#define NMID   25
#define DD     32

// Compiler memory fence + LDS-completion wait; does NOT drain vmcnt, so the
// global prefetch loads stay in flight (verified R8: passes, vs R3/R4 races).
#define FENCE asm volatile("s_waitcnt lgkmcnt(0)" ::: "memory");

// Load one mid-site tensor (site S) into an 8-float4 register buffer.
// m4 = per-chain base + lane; float4 index lane + 64*k ->
// (d = (lane>>4)+4k, p = (lane>>3)&1, e = 4*(lane&7)).
#define LOADB(BUF, S)                                                   \
    {                                                                   \
        const float4* pm_ = m4 + (size_t)(S) * 512;                     \
        _Pragma("unroll")                                               \
        for (int k = 0; k < 8; ++k) BUF[k] = pm_[64 * k];               \
    }

// R8-verbatim site body. v'[e] = sum_{d,p} v[d] * e_p * M[d][p][e].
#define COMPUTE(BUF, EI)                                                \
    {                                                                   \
        FENCE                                                           \
        const float e0_ = sE[EI][0];                                    \
        const float e1_ = sE[EI][1];                                    \
        float4 acc; acc.x = acc.y = acc.z = acc.w = 0.f;                \
        _Pragma("unroll")                                               \
        for (int k = 0; k < 8; ++k) {                                   \
            const float vd = sV[dbase + 4 * k];                         \
            acc.x = fmaf(BUF[k].x, vd, acc.x);                          \
            acc.y = fmaf(BUF[k].y, vd, acc.y);                          \
            acc.z = fmaf(BUF[k].z, vd, acc.z);                          \
            acc.w = fmaf(BUF[k].w, vd, acc.w);                          \
        }                                                               \
        _Pragma("unroll")                                               \
        for (int mask = 16; mask <= 32; mask <<= 1) {                   \
            acc.x += __shfl_xor(acc.x, mask, 64);                       \
            acc.y += __shfl_xor(acc.y, mask, 64);                       \
            acc.z += __shfl_xor(acc.z, mask, 64);                       \
            acc.w += __shfl_xor(acc.w, mask, 64);                       \
        }                                                               \
        float4 oth;                                                     \
        oth.x = __shfl_xor(acc.x, 8, 64);                               \
        oth.y = __shfl_xor(acc.y, 8, 64);                               \
        oth.z = __shfl_xor(acc.z, 8, 64);                               \
        oth.w = __shfl_xor(acc.w, 8, 64);                               \
        const float cm = p ? e1_ : e0_;                                 \
        const float co = p ? e0_ : e1_;                                 \
        float4 nv;                                                      \
        nv.x = fmaf(cm, acc.x, co * oth.x);                             \
        nv.y = fmaf(cm, acc.y, co * oth.y);                             \
        nv.z = fmaf(cm, acc.z, co * oth.z);                             \
        nv.w = fmaf(cm, acc.w, co * oth.w);                             \
        if (lane < 8) sV4[lane] = nv;                                   \
    }

// One wave per MPS chain; FIVE rotating site buffers (25 = 5x5, no tail).
// Issue-to-consume distance ~4.3 site-computes covers ~900cy HBM latency
// (0.71 waves/SIMD -> no TLP; latency must be hidden by ILP alone).
__global__ __launch_bounds__(64) void mps_layer_kernel(
    const float* __restrict__ src,    // cube of side 3*B
    const float* __restrict__ first,  // (N,2,1,32)
    const float* __restrict__ mid,    // (N,25,32,2,32)
    const float* __restrict__ last,   // (N,32,2)
    float*       __restrict__ out,    // (N)
    int B, int nChains)
{
    const int lane = threadIdx.x;
    const int n = blockIdx.x;
    if (n >= nChains) return;

    __shared__ float  sE[NSITES][2];
    __shared__ float4 sV4[8];
    float* sV = (float*)sV4;

    const int S = 3 * B;
    const int bh = n / (B * B);
    const int bv = (n / B) % B;
    const int bd = n % B;

    if (lane < NSITES) {
        const int kh = lane / 9, kv = (lane / 3) % 3, kd = lane % 3;
        const float x = src[(size_t)(bh*3 + kh) * S * S + (bv*3 + kv) * S + (bd*3 + kd)];
        float sn, cs;
        sincosf(1.5707963267948966f * x, &sn, &cs);
        sE[lane][0] = cs;
        sE[lane][1] = sn;
    }
    FENCE
    if (lane < DD) {
        const float* f = first + (size_t)n * (2 * DD);
        sV[lane] = fmaf(f[lane], sE[0][0], f[DD + lane] * sE[0][1]);
    }

    const int p     = (lane >> 3) & 1;
    const int dbase = lane >> 4;
    const float4* m4 = (const float4*)(mid + (size_t)n * NMID * 2048) + lane;

    float4 q0[8], q1[8], q2[8], q3[8], q4[8];
    LOADB(q0, 0)
    LOADB(q1, 1)
    LOADB(q2, 2)
    LOADB(q3, 3)
    LOADB(q4, 4)

    // site s lives in q{s%5}, uses sE[s+1]; loads for s+5 issue after consume.
    for (int m = 0; m < NMID; m += 5) {
        COMPUTE(q0, m + 1)
        if (m + 5 < NMID) LOADB(q0, m + 5)
        COMPUTE(q1, m + 2)
        if (m + 6 < NMID) LOADB(q1, m + 6)
        COMPUTE(q2, m + 3)
        if (m + 7 < NMID) LOADB(q2, m + 7)
        COMPUTE(q3, m + 4)
        if (m + 8 < NMID) LOADB(q3, m + 8)
        COMPUTE(q4, m + 5)
        if (m + 9 < NMID) LOADB(q4, m + 9)
    }
    FENCE

    // last site
    const float le0 = sE[26][0], le1 = sE[26][1];
    float tacc = 0.f;
    if (lane < DD) {
        const float* L = last + (size_t)n * (DD * 2);
        tacc = sV[lane] * fmaf(L[2 * lane], le0, L[2 * lane + 1] * le1);
    }
#pragma unroll
    for (int mask = 1; mask < 64; mask <<= 1) tacc += __shfl_xor(tacc, mask, 64);
    if (lane == 0) out[n] = tacc;
}

// Final-layer site step (right-to-left): u'[d] = sum_{e,p} e_p M[d][p][e] u[e].
#define FSITE(BUF, M)                                                   \
    {                                                                   \
        FENCE                                                           \
        const float e0_ = sE[(M) + 1][0];                               \
        const float e1_ = sE[(M) + 1][1];                               \
        const float ep_ = p ? e1_ : e0_;                                \
        const float4 u4 = ((const float4*)sU)[e4];                      \
        const float wx = ep_ * u4.x, wy = ep_ * u4.y;                   \
        const float wz = ep_ * u4.z, ww = ep_ * u4.w;                   \
        float acc[8];                                                   \
        _Pragma("unroll")                                               \
        for (int k = 0; k < 8; ++k) {                                   \
            const float4 Mv = BUF[k];                                   \
            acc[k] = fmaf(Mv.x, wx, fmaf(Mv.y, wy, fmaf(Mv.z, wz, Mv.w * ww))); \
        }                                                               \
        _Pragma("unroll")                                               \
        for (int mask = 1; mask <= 8; mask <<= 1) {                     \
            _Pragma("unroll")                                           \
            for (int k = 0; k < 8; ++k) acc[k] += __shfl_xor(acc[k], mask, 64); \
        }                                                               \
        if ((lane & 15) == 0) {                                         \
            _Pragma("unroll")                                           \
            for (int k = 0; k < 8; ++k) sU[dbase + 4 * k] = acc[k];     \
        }                                                               \
    }

// Final layer: output leg (O=10) on site 0 -> contract right-to-left with the
// same 5-deep rotating prefetch. u = last*e26; u <- M_m u (m=24..0);
// out[o] = sum_{p,d} ffirst[p][o][d] e0_p u[d].
__global__ __launch_bounds__(64) void mps_final_kernel(
    const float* __restrict__ x,       // out1 (27)
    const float* __restrict__ ffirst,  // (2,10,32)
    const float* __restrict__ fmid,    // (25,32,2,32)
    const float* __restrict__ flast,   // (32,2)
    float*       __restrict__ out)     // (10)
{
    const int lane = threadIdx.x;
    __shared__ float sE[NSITES][2];
    __shared__ float sU[DD];

    if (lane < NSITES) {
        float sn, cs;
        sincosf(1.5707963267948966f * x[lane], &sn, &cs);
        sE[lane][0] = cs;
        sE[lane][1] = sn;
    }
    FENCE
    if (lane < DD) {
        sU[lane] = fmaf(flast[2 * lane], sE[26][0], flast[2 * lane + 1] * sE[26][1]);
    }

    const int p     = (lane >> 3) & 1;
    const int e4    = lane & 7;
    const int dbase = lane >> 4;
    const float4* m4 = (const float4*)fmid + lane;

    float4 c0[8], c1[8], c2[8], c3[8], c4[8];
    LOADB(c0, 24)
    LOADB(c1, 23)
    LOADB(c2, 22)
    LOADB(c3, 21)
    LOADB(c4, 20)

    // t=0..4 consume sites 24-5t .. 20-5t (24..0); loads guarded >= 0.
    for (int t = 0; t < 5; ++t) {
        const int s0 = 24 - 5 * t;
        FSITE(c0, s0)
        if (s0 - 5 >= 0) LOADB(c0, s0 - 5)
        FSITE(c1, s0 - 1)
        if (s0 - 6 >= 0) LOADB(c1, s0 - 6)
        FSITE(c2, s0 - 2)
        if (s0 - 7 >= 0) LOADB(c2, s0 - 7)
        FSITE(c3, s0 - 3)
        if (s0 - 8 >= 0) LOADB(c3, s0 - 8)
        FSITE(c4, s0 - 4)
        if (s0 - 9 >= 0) LOADB(c4, s0 - 9)
    }
    FENCE

    const float e0 = sE[0][0], e1 = sE[0][1];
    const float ud = (lane < DD) ? sU[lane] : 0.f;
#pragma unroll
    for (int o = 0; o < 10; ++o) {
        float t = 0.f;
        if (lane < DD)
            t = fmaf(ffirst[o * DD + lane], e0, ffirst[320 + o * DD + lane] * e1) * ud;
#pragma unroll
        for (int mask = 1; mask < 64; mask <<= 1) t += __shfl_xor(t, mask, 64);
        if (lane == 0) out[o] = t;
    }
}

extern "C" void kernel_launch(void* const* d_in, const int* in_sizes, int n_in,
                              void* d_out, int out_size, void* d_ws, size_t ws_size,
                              hipStream_t stream) {
    const float* img = (const float*)d_in[0];
    const float* l0f = (const float*)d_in[1];
    const float* l0m = (const float*)d_in[2];
    const float* l0l = (const float*)d_in[3];
    const float* l1f = (const float*)d_in[4];
    const float* l1m = (const float*)d_in[5];
    const float* l1l = (const float*)d_in[6];
    const float* ff  = (const float*)d_in[7];
    const float* fm  = (const float*)d_in[8];
    const float* fl  = (const float*)d_in[9];
    float* out  = (float*)d_out;
    float* out0 = (float*)d_ws;        // 729 floats
    float* out1 = out0 + 729;          // 27 floats

    mps_layer_kernel<<<729, 64, 0, stream>>>(img,  l0f, l0m, l0l, out0, 9, 729);
    mps_layer_kernel<<<27,  64, 0, stream>>>(out0, l1f, l1m, l1l, out1, 3, 27);
    mps_final_kernel<<<1,   64, 0, stream>>>(out1, ff,  fm,  fl,  out);
}

// Round 11
// 269.069 us; speedup vs baseline: 1.0076x; 1.0076x over previous
//
#include <hip/hip_runtime.h>
#include <math.h>

#define NSITES 27
#define NMID   25
#define DD     32

// Load one mid-site tensor (site S) into an 8-float4 register buffer.
// m4 = per-chain base + lane; float4 index lane + 64*k ->
// (d = (lane>>4)+4k, p = (lane>>3)&1, e = 4*(lane&7)).
#define LOADB(BUF, S)                                                   \
    {                                                                   \
        const float4* pm_ = m4 + (size_t)(S) * 512;                     \
        _Pragma("unroll")                                               \
        for (int k = 0; k < 8; ++k) BUF[k] = pm_[64 * k];               \
    }

// LDS-free site step. vd[k] = v[dbase+4k] (prev site, in registers).
// v'[e] = sum_{d,p} v[d] e_p M[d][p][e]; nv = v' float4 of group e4,
// replicated across each 8-lane block. sel = nv[dbase]; next
// vd[k] = shfl(sel, (lane&56)|k)  (group k's component dbase).
#define COMPUTE(BUF, EI)                                                \
    {                                                                   \
        const float e0_ = __shfl(myCs, (EI), 64);                       \
        const float e1_ = __shfl(mySn, (EI), 64);                       \
        float4 acc; acc.x = acc.y = acc.z = acc.w = 0.f;                \
        _Pragma("unroll")                                               \
        for (int k = 0; k < 8; ++k) {                                   \
            acc.x = fmaf(BUF[k].x, vd[k], acc.x);                       \
            acc.y = fmaf(BUF[k].y, vd[k], acc.y);                       \
            acc.z = fmaf(BUF[k].z, vd[k], acc.z);                       \
            acc.w = fmaf(BUF[k].w, vd[k], acc.w);                       \
        }                                                               \
        _Pragma("unroll")                                               \
        for (int mask = 16; mask <= 32; mask <<= 1) {                   \
            acc.x += __shfl_xor(acc.x, mask, 64);                       \
            acc.y += __shfl_xor(acc.y, mask, 64);                       \
            acc.z += __shfl_xor(acc.z, mask, 64);                       \
            acc.w += __shfl_xor(acc.w, mask, 64);                       \
        }                                                               \
        float4 oth;                                                     \
        oth.x = __shfl_xor(acc.x, 8, 64);                               \
        oth.y = __shfl_xor(acc.y, 8, 64);                               \
        oth.z = __shfl_xor(acc.z, 8, 64);                               \
        oth.w = __shfl_xor(acc.w, 8, 64);                               \
        const float cm = p ? e1_ : e0_;                                 \
        const float co = p ? e0_ : e1_;                                 \
        float4 nv;                                                      \
        nv.x = fmaf(cm, acc.x, co * oth.x);                             \
        nv.y = fmaf(cm, acc.y, co * oth.y);                             \
        nv.z = fmaf(cm, acc.z, co * oth.z);                             \
        nv.w = fmaf(cm, acc.w, co * oth.w);                             \
        sel = (dbase == 0) ? nv.x : (dbase == 1) ? nv.y                 \
            : (dbase == 2) ? nv.z : nv.w;                               \
        _Pragma("unroll")                                               \
        for (int k = 0; k < 8; ++k)                                     \
            vd[k] = __shfl(sel, selbase | k, 64);                       \
    }

// One wave per MPS chain; five rotating register buffers; no LDS anywhere.
__global__ __launch_bounds__(64) void mps_layer_kernel(
    const float* __restrict__ src,    // cube of side 3*B
    const float* __restrict__ first,  // (N,2,1,32)
    const float* __restrict__ mid,    // (N,25,32,2,32)
    const float* __restrict__ last,   // (N,32,2)
    float*       __restrict__ out,    // (N)
    int B, int nChains)
{
    const int lane = threadIdx.x;
    const int n = blockIdx.x;
    if (n >= nChains) return;

    const int p       = (lane >> 3) & 1;
    const int dbase   = lane >> 4;
    const int selbase = lane & 56;
    const float4* m4 = (const float4*)(mid + (size_t)n * NMID * 2048) + lane;

    // issue the deep prefetch first so it overlaps the sincos prologue
    float4 q0[8], q1[8], q2[8], q3[8], q4[8];
    LOADB(q0, 0)
    LOADB(q1, 1)
    LOADB(q2, 2)
    LOADB(q3, 3)
    LOADB(q4, 4)

    // per-lane embedding for site = lane (lanes 0..26; others clamp, unused)
    const int S = 3 * B;
    const int bh = n / (B * B);
    const int bv = (n / B) % B;
    const int bd = n % B;
    float myCs, mySn;
    {
        const int s  = lane < NSITES ? lane : NSITES - 1;
        const int kh = s / 9, kv = (s / 3) % 3, kd = s % 3;
        const float x = src[(size_t)(bh*3 + kh) * S * S + (bv*3 + kv) * S + (bd*3 + kd)];
        sincosf(1.5707963267948966f * x, &mySn, &myCs);
    }

    // initial vd[k] = v0[dbase+4k]; v0[d] = first[0][d]*cs0 + first[1][d]*sn0
    const float cs0 = __shfl(myCs, 0, 64);
    const float sn0 = __shfl(mySn, 0, 64);
    const float* f = first + (size_t)n * (2 * DD);
    float vd[8];
    float sel;
#pragma unroll
    for (int k = 0; k < 8; ++k) {
        const int d = dbase + 4 * k;
        vd[k] = fmaf(f[d], cs0, f[DD + d] * sn0);
    }

    // site s lives in q{s%5}, uses embedding s+1; loads for s+5 after consume.
    for (int m = 0; m < NMID; m += 5) {
        COMPUTE(q0, m + 1)
        if (m + 5 < NMID) LOADB(q0, m + 5)
        COMPUTE(q1, m + 2)
        if (m + 6 < NMID) LOADB(q1, m + 6)
        COMPUTE(q2, m + 3)
        if (m + 7 < NMID) LOADB(q2, m + 7)
        COMPUTE(q3, m + 4)
        if (m + 8 < NMID) LOADB(q3, m + 8)
        COMPUTE(q4, m + 5)
        if (m + 9 < NMID) LOADB(q4, m + 9)
    }

    // last site: v[lane&31] = comp (lane&3) of group ((lane&31)>>2)
    const float le0 = __shfl(myCs, 26, 64);
    const float le1 = __shfl(mySn, 26, 64);
    const float vL  = __shfl(sel, ((lane & 3) << 4) | ((lane & 31) >> 2), 64);
    float tacc = 0.f;
    if (lane < DD) {
        const float* L = last + (size_t)n * (DD * 2);
        tacc = vL * fmaf(L[2 * lane], le0, L[2 * lane + 1] * le1);
    }
#pragma unroll
    for (int mask = 1; mask < 64; mask <<= 1) tacc += __shfl_xor(tacc, mask, 64);
    if (lane == 0) out[n] = tacc;
}

// Final-layer site step (right-to-left), LDS-free.
// u4 = u[4e4..4e4+3] (registers). acc[k] = u'[4k+dbase] after the bit0-3
// reduce (replicated per 16-lane group). usel = acc[e4]; next
// u4.c = shfl(usel, (c<<4)|(lane&15)).
#define FSITE(BUF, M)                                                   \
    {                                                                   \
        const float e0_ = __shfl(myCs, (M) + 1, 64);                    \
        const float e1_ = __shfl(mySn, (M) + 1, 64);                    \
        const float ep_ = p ? e1_ : e0_;                                \
        const float wx = ep_ * u4.x, wy = ep_ * u4.y;                   \
        const float wz = ep_ * u4.z, ww = ep_ * u4.w;                   \
        float acc[8];                                                   \
        _Pragma("unroll")                                               \
        for (int k = 0; k < 8; ++k) {                                   \
            const float4 Mv = BUF[k];                                   \
            acc[k] = fmaf(Mv.x, wx, fmaf(Mv.y, wy, fmaf(Mv.z, wz, Mv.w * ww))); \
        }                                                               \
        _Pragma("unroll")                                               \
        for (int mask = 1; mask <= 8; mask <<= 1) {                     \
            _Pragma("unroll")                                           \
            for (int k = 0; k < 8; ++k) acc[k] += __shfl_xor(acc[k], mask, 64); \
        }                                                               \
        {                                                               \
            const float t01 = (e4 & 1) ? acc[1] : acc[0];               \
            const float t23 = (e4 & 1) ? acc[3] : acc[2];               \
            const float t45 = (e4 & 1) ? acc[5] : acc[4];               \
            const float t67 = (e4 & 1) ? acc[7] : acc[6];               \
            const float t03 = (e4 & 2) ? t23 : t01;                     \
            const float t47 = (e4 & 2) ? t67 : t45;                     \
            usel = (e4 & 4) ? t47 : t03;                                \
        }                                                               \
        u4.x = __shfl(usel, (lane & 15),      64);                      \
        u4.y = __shfl(usel, (lane & 15) | 16, 64);                      \
        u4.z = __shfl(usel, (lane & 15) | 32, 64);                      \
        u4.w = __shfl(usel, (lane & 15) | 48, 64);                      \
    }

// Final layer: output leg (O=10) on site 0 -> contract right-to-left with
// the 5-deep rotating prefetch; LDS-free.
__global__ __launch_bounds__(64) void mps_final_kernel(
    const float* __restrict__ x,       // out1 (27)
    const float* __restrict__ ffirst,  // (2,10,32)
    const float* __restrict__ fmid,    // (25,32,2,32)
    const float* __restrict__ flast,   // (32,2)
    float*       __restrict__ out)     // (10)
{
    const int lane = threadIdx.x;
    const int p     = (lane >> 3) & 1;
    const int e4    = lane & 7;
    const float4* m4 = (const float4*)fmid + lane;

    float4 c0[8], c1[8], c2[8], c3[8], c4[8];
    LOADB(c0, 24)
    LOADB(c1, 23)
    LOADB(c2, 22)
    LOADB(c3, 21)
    LOADB(c4, 20)

    float myCs, mySn;
    {
        const int s = lane < NSITES ? lane : NSITES - 1;
        sincosf(1.5707963267948966f * x[s], &mySn, &myCs);
    }

    // initial u4 = u[4e4..4e4+3]; u[d] = flast[2d]*cs26 + flast[2d+1]*sn26
    const float cs26 = __shfl(myCs, 26, 64);
    const float sn26 = __shfl(mySn, 26, 64);
    float4 u4;
    {
        const int d0 = 4 * e4;
        u4.x = fmaf(flast[2*d0    ], cs26, flast[2*d0 + 1] * sn26);
        u4.y = fmaf(flast[2*d0 + 2], cs26, flast[2*d0 + 3] * sn26);
        u4.z = fmaf(flast[2*d0 + 4], cs26, flast[2*d0 + 5] * sn26);
        u4.w = fmaf(flast[2*d0 + 6], cs26, flast[2*d0 + 7] * sn26);
    }
    float usel;

    // t=0..4 consume sites 24-5t .. 20-5t (24..0); loads guarded >= 0.
    for (int t = 0; t < 5; ++t) {
        const int s0 = 24 - 5 * t;
        FSITE(c0, s0)
        if (s0 - 5 >= 0) LOADB(c0, s0 - 5)
        FSITE(c1, s0 - 1)
        if (s0 - 6 >= 0) LOADB(c1, s0 - 6)
        FSITE(c2, s0 - 2)
        if (s0 - 7 >= 0) LOADB(c2, s0 - 7)
        FSITE(c3, s0 - 3)
        if (s0 - 8 >= 0) LOADB(c3, s0 - 8)
        FSITE(c4, s0 - 4)
        if (s0 - 9 >= 0) LOADB(c4, s0 - 9)
    }

    // full u[lane&31] for the output contraction
    const float ud0 = __shfl(usel, ((lane & 3) << 4) | ((lane & 31) >> 2), 64);
    const float e0 = __shfl(myCs, 0, 64);
    const float e1 = __shfl(mySn, 0, 64);
    const float ud = (lane < DD) ? ud0 : 0.f;
#pragma unroll
    for (int o = 0; o < 10; ++o) {
        float t = 0.f;
        if (lane < DD)
            t = fmaf(ffirst[o * DD + lane], e0, ffirst[320 + o * DD + lane] * e1) * ud;
#pragma unroll
        for (int mask = 1; mask < 64; mask <<= 1) t += __shfl_xor(t, mask, 64);
        if (lane == 0) out[o] = t;
    }
}

extern "C" void kernel_launch(void* const* d_in, const int* in_sizes, int n_in,
                              void* d_out, int out_size, void* d_ws, size_t ws_size,
                              hipStream_t stream) {
    const float* img = (const float*)d_in[0];
    const float* l0f = (const float*)d_in[1];
    const float* l0m = (const float*)d_in[2];
    const float* l0l = (const float*)d_in[3];
    const float* l1f = (const float*)d_in[4];
    const float* l1m = (const float*)d_in[5];
    const float* l1l = (const float*)d_in[6];
    const float* ff  = (const float*)d_in[7];
    const float* fm  = (const float*)d_in[8];
    const float* fl  = (const float*)d_in[9];
    float* out  = (float*)d_out;
    float* out0 = (float*)d_ws;        // 729 floats
    float* out1 = out0 + 729;          // 27 floats

    mps_layer_kernel<<<729, 64, 0, stream>>>(img,  l0f, l0m, l0l, out0, 9, 729);
    mps_layer_kernel<<<27,  64, 0, stream>>>(out0, l1f, l1m, l1l, out1, 3, 27);
    mps_final_kernel<<<1,   64, 0, stream>>>(out1, ff,  fm,  fl,  out);
}